// Round 6
// baseline (136.956 us; speedup 1.0000x reference)
//
#include <hip/hip_runtime.h>
#include <math.h>

#define DIM 4096
#define NH 32
#define NKV 8
#define HD 128
#define NREP 4
#define TILE 4      // positions per tile
#define NBUF 4      // rotating LDS tile buffers (3 tiles prefetch depth)

// ---------------------------------------------------------------------------
// Kernel 1: q/k/v GEMV + fused RoPE (unchanged from R5).
// ---------------------------------------------------------------------------
__global__ __launch_bounds__(256) void qkv_rope_kernel(
    const float* __restrict__ x, const float* __restrict__ fc,
    const float* __restrict__ fs, const float* __restrict__ wq,
    const float* __restrict__ wk, const float* __restrict__ wv,
    float* __restrict__ q_rope, float* __restrict__ k_new,
    float* __restrict__ v_new) {
  int wave = blockIdx.x * 4 + (threadIdx.x >> 6);
  int lane = threadIdx.x & 63;
  const float* W;
  float* dst;
  int r0;
  bool rope;
  if (wave < 2048) {            // q: 4096 rows
    W = wq; dst = q_rope; r0 = wave * 2; rope = true;
  } else if (wave < 2560) {     // k: 1024 rows
    W = wk; dst = k_new; r0 = (wave - 2048) * 2; rope = true;
  } else {                      // v: 1024 rows
    W = wv; dst = v_new; r0 = (wave - 2560) * 2; rope = false;
  }
  const float4* x4 = (const float4*)x;
  const float4* w0 = (const float4*)(W + (size_t)r0 * DIM);
  const float4* w1 = (const float4*)(W + (size_t)(r0 + 1) * DIM);
  float a0 = 0.f, a1 = 0.f;
#pragma unroll 4
  for (int c = lane; c < DIM / 4; c += 64) {
    float4 xv = x4[c];
    float4 u = w0[c];
    float4 v = w1[c];
    a0 += xv.x * u.x + xv.y * u.y + xv.z * u.z + xv.w * u.w;
    a1 += xv.x * v.x + xv.y * v.y + xv.z * v.z + xv.w * v.w;
  }
  for (int off = 32; off > 0; off >>= 1) {
    a0 += __shfl_down(a0, off, 64);
    a1 += __shfl_down(a1, off, 64);
  }
  if (lane == 0) {
    if (rope) {
      int j = (r0 & (HD - 1)) >> 1;
      float c = fc[j], s = fs[j];
      dst[r0]     = a0 * c - a1 * s;
      dst[r0 + 1] = a0 * s + a1 * c;
    } else {
      dst[r0]     = a0;
      dst[r0 + 1] = a1;
    }
  }
}

#define LD4(p) (*(const float4*)(p))

#define GLL(src, dst)                                                       \
  __builtin_amdgcn_global_load_lds(                                         \
      (const __attribute__((address_space(1))) void*)(src),                 \
      (__attribute__((address_space(3))) void*)(dst), 16, 0, 0)

// Stage tile n_: wave wvi stages position (t0 + n_*TILE + wvi): full 4KB K
// row + 4KB V row as 8 x 1KB fully-contiguous DMA instructions.
// Invalid positions stage k_new/v_new (4KB each) so vmcnt counts stay uniform.
#define STAGE(n_)                                                           \
  {                                                                         \
    int tt = t0 + (n_) * TILE + wvi;                                        \
    const float* gk;                                                        \
    const float* gv;                                                        \
    if (tt < start_pos) {                                                   \
      gk = k_cache + (size_t)tt * (NKV * HD);                               \
      gv = v_cache + (size_t)tt * (NKV * HD);                               \
    } else {                                                                \
      gk = k_new;                                                           \
      gv = v_new;                                                           \
    }                                                                       \
    int bb = (n_) & (NBUF - 1);                                             \
    float* kd = &smem[((bb * 2 + 0) * TILE + wvi) * 1024];                  \
    float* vd = &smem[((bb * 2 + 1) * TILE + wvi) * 1024];                  \
    GLL(gk + lane * 4, kd);                                                 \
    GLL(gk + 256 + lane * 4, kd + 256);                                     \
    GLL(gk + 512 + lane * 4, kd + 512);                                     \
    GLL(gk + 768 + lane * 4, kd + 768);                                     \
    GLL(gv + lane * 4, vd);                                                 \
    GLL(gv + 256 + lane * 4, vd + 256);                                     \
    GLL(gv + 512 + lane * 4, vd + 512);                                     \
    GLL(gv + 768 + lane * 4, vd + 768);                                     \
  }

// ---------------------------------------------------------------------------
// Kernel 2: flash-decode partials, t-only partitioning (contiguous HBM).
// Block = contiguous t-range; handles ALL 8 kv-heads / 32 q-heads.
// Wave wvi owns d-quarter [32*wvi, 32*wvi+32). Lane = (g = lane>>3,
// d4 = lane&7): 4-float slice. Per tile (4 positions):
//   phase1: per-pos K dots (4 heads/g) -> 8-lane transposed reduce ->
//           partial scores to LDS s_ps[wave][pos][head]
//   phase2: threads 0-127 finish score (sum 4 wave-quarters), exp (m=0
//           reference, fp32-safe: validated R4/R5), lsum accumulate
//   phase3: PV accumulate into acc[4 heads][4 floats] per lane
// Raw s_barrier + counted vmcnt (never drained mid-stream); DMA 3 tiles deep.
// ---------------------------------------------------------------------------
__global__ __launch_bounds__(256, 1) void attn_partial_kernel(
    const float* __restrict__ q_rope, const float* __restrict__ k_cache,
    const float* __restrict__ v_cache, const float* __restrict__ k_new,
    const float* __restrict__ v_new, float* __restrict__ partial_l,
    float* __restrict__ partial_o, int start_pos, int PB, int nsplit) {
  int split = blockIdx.x;
  int t0 = split * PB;
  int tid = threadIdx.x;
  int wvi = tid >> 6;
  int lane = tid & 63;
  int g = lane >> 3;
  int d4 = lane & 7;
  int qoff = wvi * 32 + d4 * 4;   // this lane's d-slice
  const float scale = 0.08838834764831845f;  // 1/sqrt(128)

  __shared__ float smem[NBUF * 2 * TILE * 1024];  // 128 KB K/V tiles
  __shared__ float s_ps[4][TILE][NH];             // per-wave partial scores
  __shared__ float s_e[TILE][NH];                 // probs
  __shared__ float s_l[TILE * NH];                // lsum combine

  // q fragments: head h = g*4+j, dims [qoff, qoff+4)
  float qf[4][4];
#pragma unroll
  for (int j = 0; j < 4; ++j) {
    float4 q4 = LD4(q_rope + (g * 4 + j) * HD + qoff);
    qf[j][0] = q4.x; qf[j][1] = q4.y; qf[j][2] = q4.z; qf[j][3] = q4.w;
  }
  float acc[4][4];
#pragma unroll
  for (int j = 0; j < 4; ++j)
#pragma unroll
    for (int e = 0; e < 4; ++e) acc[j][e] = 0.f;
  float lsum = 0.f;

  int NT = PB / TILE;

  asm volatile("s_waitcnt vmcnt(0)" ::: "memory");  // drain q loads
  __builtin_amdgcn_sched_barrier(0);
  STAGE(0);
  STAGE(1);
  STAGE(2);

  for (int n = 0; n < NT; ++n) {
    // wait for tile n (8 DMA instr/wave/tile; keep later tiles in flight)
    if (n + 2 < NT) {
      asm volatile("s_waitcnt vmcnt(16)" ::: "memory");
    } else if (n + 1 < NT) {
      asm volatile("s_waitcnt vmcnt(8)" ::: "memory");
    } else {
      asm volatile("s_waitcnt vmcnt(0)" ::: "memory");
    }
    __builtin_amdgcn_sched_barrier(0);
    __builtin_amdgcn_s_barrier();
    __builtin_amdgcn_sched_barrier(0);
    if (n + 3 < NT) STAGE(n + 3);

    int b = n & (NBUF - 1);
    int tbase = t0 + n * TILE;

    // ---- phase 1: K dots ----
#pragma unroll
    for (int p = 0; p < TILE; ++p) {
      const float* kr =
          &smem[((b * 2 + 0) * TILE + p) * 1024 + g * HD + qoff];
      float4 K4 = LD4(kr);
      float s0 = K4.x * qf[0][0] + K4.y * qf[0][1] + K4.z * qf[0][2] +
                 K4.w * qf[0][3];
      float s1 = K4.x * qf[1][0] + K4.y * qf[1][1] + K4.z * qf[1][2] +
                 K4.w * qf[1][3];
      float s2 = K4.x * qf[2][0] + K4.y * qf[2][1] + K4.z * qf[2][2] +
                 K4.w * qf[2][3];
      float s3 = K4.x * qf[3][0] + K4.y * qf[3][1] + K4.z * qf[3][2] +
                 K4.w * qf[3][3];
      // transposed reduce over the 8 lanes of this g: lane d4=j ends with
      // s_j summed over all 8 d-slices (4 shuffles)
      bool o1 = (d4 & 1) != 0, o2 = (d4 & 2) != 0;
      float x0 = o1 ? s0 : s1, k0 = o1 ? s1 : s0;
      float v1 = k0 + __shfl_xor(x0, 1, 64);
      float x1 = o1 ? s2 : s3, k1 = o1 ? s3 : s2;
      float v2 = k1 + __shfl_xor(x1, 1, 64);
      float x2 = o2 ? v1 : v2, k2 = o2 ? v2 : v1;
      float u = k2 + __shfl_xor(x2, 2, 64);
      u += __shfl_xor(u, 4, 64);
      bool validp = (tbase + p) < start_pos;
      if ((lane & 4) == 0)
        s_ps[wvi][p][g * 4 + (lane & 3)] = validp ? u : -1e30f;
    }
    asm volatile("s_waitcnt lgkmcnt(0)" ::: "memory");
    __builtin_amdgcn_sched_barrier(0);
    __builtin_amdgcn_s_barrier();
    __builtin_amdgcn_sched_barrier(0);

    // ---- phase 2: finish scores, exp, lsum ----
    if (tid < TILE * NH) {
      int p = tid >> 5, h = tid & 31;
      float ps = s_ps[0][p][h] + s_ps[1][p][h] + s_ps[2][p][h] +
                 s_ps[3][p][h];
      float e = __expf(ps * scale);
      s_e[p][h] = e;
      lsum += e;
    }
    asm volatile("s_waitcnt lgkmcnt(0)" ::: "memory");
    __builtin_amdgcn_sched_barrier(0);
    __builtin_amdgcn_s_barrier();
    __builtin_amdgcn_sched_barrier(0);

    // ---- phase 3: PV accumulate ----
#pragma unroll
    for (int p = 0; p < TILE; ++p) {
      float e0 = s_e[p][g * 4 + 0];
      float e1 = s_e[p][g * 4 + 1];
      float e2 = s_e[p][g * 4 + 2];
      float e3 = s_e[p][g * 4 + 3];
      const float* vr =
          &smem[((b * 2 + 1) * TILE + p) * 1024 + g * HD + qoff];
      float4 V4 = LD4(vr);
      acc[0][0] += e0 * V4.x; acc[0][1] += e0 * V4.y;
      acc[0][2] += e0 * V4.z; acc[0][3] += e0 * V4.w;
      acc[1][0] += e1 * V4.x; acc[1][1] += e1 * V4.y;
      acc[1][2] += e1 * V4.z; acc[1][3] += e1 * V4.w;
      acc[2][0] += e2 * V4.x; acc[2][1] += e2 * V4.y;
      acc[2][2] += e2 * V4.z; acc[2][3] += e2 * V4.w;
      acc[3][0] += e3 * V4.x; acc[3][1] += e3 * V4.y;
      acc[3][2] += e3 * V4.z; acc[3][3] += e3 * V4.w;
    }
  }

  __syncthreads();
  if (tid < TILE * NH) s_l[tid] = lsum;
  __syncthreads();
  if (tid < NH) {
    partial_l[tid * nsplit + split] =
        s_l[tid] + s_l[32 + tid] + s_l[64 + tid] + s_l[96 + tid];
  }
  // acc write-out: lane's d-slice of heads g*4+j
#pragma unroll
  for (int j = 0; j < 4; ++j) {
    float4 o4;
    o4.x = acc[j][0]; o4.y = acc[j][1]; o4.z = acc[j][2]; o4.w = acc[j][3];
    *(float4*)&partial_o[((size_t)(g * 4 + j) * nsplit + split) * HD + qoff] =
        o4;
  }
}

// ---------------------------------------------------------------------------
// Kernel 3: combine splits + new-token contribution. Block per head,
// 128 threads (one per d). All partial m == 0.
// ---------------------------------------------------------------------------
__global__ __launch_bounds__(128) void combine_kernel(
    const float* __restrict__ q_rope, const float* __restrict__ k_new,
    const float* __restrict__ v_new, const float* __restrict__ partial_l,
    const float* __restrict__ partial_o, float* __restrict__ attn_out,
    int nsplit) {
  int h = blockIdx.x;
  int g = h >> 2;
  int tid = threadIdx.x;
  __shared__ float sl[512];
  __shared__ float sp[128];
  sp[tid] = q_rope[h * HD + tid] * k_new[g * HD + tid];
  for (int i = tid; i < nsplit; i += 128) sl[i] = partial_l[h * nsplit + i];
  __syncthreads();
  for (int s = 64; s > 0; s >>= 1) {
    if (tid < s) sp[tid] += sp[tid + s];
    __syncthreads();
  }
  float e_new = __expf(sp[0] * 0.08838834764831845f);
  float L = e_new;
  for (int s = 0; s < nsplit; ++s) L += sl[s];
  float acc = e_new * v_new[g * HD + tid];
#pragma unroll 4
  for (int s = 0; s < nsplit; ++s)
    acc += partial_o[((size_t)h * nsplit + s) * HD + tid];
  attn_out[h * HD + tid] = acc / L;
}

// ---------------------------------------------------------------------------
// Kernel 4: out = attn @ wo.T (unchanged).
// ---------------------------------------------------------------------------
__global__ __launch_bounds__(256) void out_gemv_kernel(
    const float* __restrict__ attn, const float* __restrict__ wo,
    float* __restrict__ out) {
  int row = blockIdx.x * 4 + (threadIdx.x >> 6);
  int lane = threadIdx.x & 63;
  const float4* a4 = (const float4*)attn;
  const float4* w4 = (const float4*)(wo + (size_t)row * DIM);
  float a = 0.f;
#pragma unroll 4
  for (int c = lane; c < DIM / 4; c += 64) {
    float4 av = a4[c];
    float4 wv = w4[c];
    a += av.x * wv.x + av.y * wv.y + av.z * wv.z + av.w * wv.w;
  }
  for (int off = 32; off > 0; off >>= 1) a += __shfl_down(a, off, 64);
  if (lane == 0) out[row] = a;
}

extern "C" void kernel_launch(void* const* d_in, const int* in_sizes, int n_in,
                              void* d_out, int out_size, void* d_ws,
                              size_t ws_size, hipStream_t stream) {
  const float* x       = (const float*)d_in[0];
  const float* fc      = (const float*)d_in[1];
  const float* fs      = (const float*)d_in[2];
  const float* k_cache = (const float*)d_in[3];
  const float* v_cache = (const float*)d_in[4];
  const float* wq      = (const float*)d_in[5];
  const float* wk      = (const float*)d_in[6];
  const float* wv      = (const float*)d_in[7];
  const float* wo      = (const float*)d_in[8];
  float* out = (float*)d_out;

  int start_pos = in_sizes[3] / (NKV * HD);  // cache length (32767)

  // pick split count to fit workspace
  int nsplit = 256;
  if ((size_t)(10240 + 32 * nsplit * (HD + 1)) * 4 > ws_size) nsplit = 128;
  // positions per block, multiple of TILE, covering [0, start_pos)
  int PB = ((start_pos + nsplit - 1) / nsplit + TILE - 1) & ~(TILE - 1);

  float* ws = (float*)d_ws;
  float* q_rope    = ws;                        // 4096
  float* k_new     = ws + 4096;                 // 1024
  float* v_new     = ws + 5120;                 // 1024
  float* attn_out  = ws + 6144;                 // 4096
  float* partial_l = ws + 10240;                // 32*nsplit
  float* partial_o = partial_l + NH * nsplit;   // 32*nsplit*128

  qkv_rope_kernel<<<768, 256, 0, stream>>>(x, fc, fs, wq, wk, wv, q_rope,
                                           k_new, v_new);
  attn_partial_kernel<<<nsplit, 256, 0, stream>>>(
      q_rope, k_cache, v_cache, k_new, v_new, partial_l, partial_o,
      start_pos, PB, nsplit);
  combine_kernel<<<NH, 128, 0, stream>>>(q_rope, k_new, v_new, partial_l,
                                         partial_o, attn_out, nsplit);
  out_gemv_kernel<<<1024, 256, 0, stream>>>(attn_out, wo, out);
}

// Round 7
// 97.109 us; speedup vs baseline: 1.4103x; 1.4103x over previous
//
#include <hip/hip_runtime.h>
#include <math.h>

#define DIM 4096
#define NH 32
#define NKV 8
#define HD 128
#define NREP 4
#define PBLK 1024           // positions per block
#define PWAVE 256           // positions per wave
#define TILE 8              // positions per tile: 4KB K + 4KB V
#define NTW (PWAVE / TILE)  // 32 tiles per wave
#define NBUF 4
#define BUF_F 2048          // floats per buffer (K 1024 | V 1024)
#define WAVE_F (NBUF * BUF_F)

// ---------------------------------------------------------------------------
// Kernel 1: q/k/v GEMV + fused RoPE (unchanged).
// ---------------------------------------------------------------------------
__global__ __launch_bounds__(256) void qkv_rope_kernel(
    const float* __restrict__ x, const float* __restrict__ fc,
    const float* __restrict__ fs, const float* __restrict__ wq,
    const float* __restrict__ wk, const float* __restrict__ wv,
    float* __restrict__ q_rope, float* __restrict__ k_new,
    float* __restrict__ v_new) {
  int wave = blockIdx.x * 4 + (threadIdx.x >> 6);
  int lane = threadIdx.x & 63;
  const float* W;
  float* dst;
  int r0;
  bool rope;
  if (wave < 2048) {
    W = wq; dst = q_rope; r0 = wave * 2; rope = true;
  } else if (wave < 2560) {
    W = wk; dst = k_new; r0 = (wave - 2048) * 2; rope = true;
  } else {
    W = wv; dst = v_new; r0 = (wave - 2560) * 2; rope = false;
  }
  const float4* x4 = (const float4*)x;
  const float4* w0 = (const float4*)(W + (size_t)r0 * DIM);
  const float4* w1 = (const float4*)(W + (size_t)(r0 + 1) * DIM);
  float a0 = 0.f, a1 = 0.f;
#pragma unroll 4
  for (int c = lane; c < DIM / 4; c += 64) {
    float4 xv = x4[c];
    float4 u = w0[c];
    float4 v = w1[c];
    a0 += xv.x * u.x + xv.y * u.y + xv.z * u.z + xv.w * u.w;
    a1 += xv.x * v.x + xv.y * v.y + xv.z * v.z + xv.w * v.w;
  }
  for (int off = 32; off > 0; off >>= 1) {
    a0 += __shfl_down(a0, off, 64);
    a1 += __shfl_down(a1, off, 64);
  }
  if (lane == 0) {
    if (rope) {
      int jj = (r0 & (HD - 1)) >> 1;
      float c = fc[jj], s = fs[jj];
      dst[r0]     = a0 * c - a1 * s;
      dst[r0 + 1] = a0 * s + a1 * c;
    } else {
      dst[r0]     = a0;
      dst[r0 + 1] = a1;
    }
  }
}

#define LD4(p) (*(const float4*)(p))

#define GLL(src, dst)                                                       \
  __builtin_amdgcn_global_load_lds(                                         \
      (const __attribute__((address_space(1))) void*)(src),                 \
      (__attribute__((address_space(3))) void*)(dst), 16, 0, 0)

// Stage tile n_ of this wave into its private ring buffer. 8 x 1KB DMA.
// Dest is LINEAR (HW requirement); the XOR-granule swizzle (granule j of
// row r holds global granule j^r) is applied on the per-lane GLOBAL source
// (both-sides-or-neither rule). Out-of-range rows clamp to k_new/v_new.
__device__ __forceinline__ void stage_tile(
    int n_, int w, int rhalf, int jg, int t0w, int gid, int start_pos,
    const float* k_cache, const float* v_cache, const float* k_new,
    const float* v_new, float* smem) {
  int bb = n_ & (NBUF - 1);
  float* kd = &smem[w * WAVE_F + bb * BUF_F];
  float* vd = kd + 1024;
#pragma unroll
  for (int ki = 0; ki < 4; ++ki) {
    int r = ki * 2 + rhalf;                  // row-in-tile 0..7 (swizzle key)
    int tg = t0w + n_ * TILE + r;
    int soff = (jg ^ r) << 2;                // swizzled source granule
    const float* sk;
    const float* sv;
    if (tg < start_pos) {
      sk = k_cache + ((size_t)tg * NKV + gid) * HD + soff;
      sv = v_cache + ((size_t)tg * NKV + gid) * HD + soff;
    } else {
      sk = k_new + gid * HD + soff;
      sv = v_new + gid * HD + soff;
    }
    GLL(sk, kd + ki * 256);
    GLL(sv, vd + ki * 256);
  }
}

// ---------------------------------------------------------------------------
// Kernel 2: flash-decode partials (m=0 reference, validated R4/R5).
// Block = (kv-head gid, 1024-position split). 4 waves, each with a PRIVATE
// 32KB LDS ring over its own contiguous 256 positions -> NO barriers in the
// main loop; only per-wave counted vmcnt + one lgkmcnt fence per 8-pos tile.
// QK^T: lane=(t=l&7, q8=l>>3) -> 4 indep swizzled ds_read_b128 + 64 FMA,
//   ONE 3-shuffle butterfly + exp per 8 positions.
// PV: lane=(head j=l>>4, slot ds=l&15) accumulates out[8] in registers over
//   all positions -- zero cross-lane ops until block end.
// ---------------------------------------------------------------------------
__global__ __launch_bounds__(256, 1) void attn_partial_kernel(
    const float* __restrict__ q_rope, const float* __restrict__ k_cache,
    const float* __restrict__ v_cache, const float* __restrict__ k_new,
    const float* __restrict__ v_new, float* __restrict__ partial_l,
    float* __restrict__ partial_o, int start_pos, int nsplit) {
  int gid = blockIdx.x & 7;
  int split = blockIdx.x >> 3;
  int tid = threadIdx.x;
  int w = tid >> 6;
  int l = tid & 63;
  int t0w = split * PBLK + w * PWAVE;

  __shared__ float smem[4 * WAVE_F];        // 128 KB: 4 wave-private rings
  __shared__ float p_lds[4][TILE][NREP];    // per-wave probs (one tile)
  __shared__ float out_comb[4][NREP][HD];   // cross-wave combine
  __shared__ float l_comb[4][NREP];

  int t = l & 7;       // QK^T row-in-tile
  int q8 = l >> 3;     // QK^T d-sixteenth
  int j = l >> 4;      // PV head
  int ds = l & 15;     // PV d-slot (8 floats)
  int rhalf = l >> 5;  // staging: row within pair
  int jg = l & 31;     // staging: dest granule within row

  const float scale = 0.08838834764831845f;  // 1/sqrt(128)

  // q fragments for QK^T: head h, dims [q8*16, q8*16+16)
  float4 qf[NREP][4];
#pragma unroll
  for (int h = 0; h < NREP; ++h)
#pragma unroll
    for (int cc = 0; cc < 4; ++cc)
      qf[h][cc] = LD4(q_rope + (gid * NREP + h) * HD + q8 * 16 + cc * 4);

  float lsum[NREP] = {0.f, 0.f, 0.f, 0.f};
  float out[8] = {0.f, 0.f, 0.f, 0.f, 0.f, 0.f, 0.f, 0.f};

  asm volatile("s_waitcnt vmcnt(0)" ::: "memory");  // drain q loads
  __builtin_amdgcn_sched_barrier(0);
  stage_tile(0, w, rhalf, jg, t0w, gid, start_pos, k_cache, v_cache, k_new,
             v_new, smem);
  stage_tile(1, w, rhalf, jg, t0w, gid, start_pos, k_cache, v_cache, k_new,
             v_new, smem);

  for (int n = 0; n < NTW; ++n) {
    // issue tile n+2 (clamped past range; buffer (n+2)&3 consumed 2 ago and
    // its readers drained by last iteration's lgkmcnt fence)
    stage_tile(n + 2, w, rhalf, jg, t0w, gid, start_pos, k_cache, v_cache,
               k_new, v_new, smem);
    asm volatile("s_waitcnt vmcnt(16)" ::: "memory");  // tile n landed
    __builtin_amdgcn_sched_barrier(0);

    const float* kb = &smem[w * WAVE_F + (n & (NBUF - 1)) * BUF_F];
    // ---- QK^T ----
    float s0 = 0.f, s1 = 0.f, s2 = 0.f, s3 = 0.f;
#pragma unroll
    for (int cc = 0; cc < 4; ++cc) {
      float4 K4 = LD4(kb + t * 128 + (((q8 * 4 + cc) ^ t) << 2));
      s0 += K4.x * qf[0][cc].x + K4.y * qf[0][cc].y + K4.z * qf[0][cc].z +
            K4.w * qf[0][cc].w;
      s1 += K4.x * qf[1][cc].x + K4.y * qf[1][cc].y + K4.z * qf[1][cc].z +
            K4.w * qf[1][cc].w;
      s2 += K4.x * qf[2][cc].x + K4.y * qf[2][cc].y + K4.z * qf[2][cc].z +
            K4.w * qf[2][cc].w;
      s3 += K4.x * qf[3][cc].x + K4.y * qf[3][cc].y + K4.z * qf[3][cc].z +
            K4.w * qf[3][cc].w;
    }
#pragma unroll
    for (int m = 8; m <= 32; m <<= 1) {
      s0 += __shfl_xor(s0, m, 64);
      s1 += __shfl_xor(s1, m, 64);
      s2 += __shfl_xor(s2, m, 64);
      s3 += __shfl_xor(s3, m, 64);
    }
    int tg = t0w + n * TILE + t;
    bool valid = tg < start_pos;
    float p0 = valid ? __expf(s0 * scale) : 0.f;
    float p1 = valid ? __expf(s1 * scale) : 0.f;
    float p2 = valid ? __expf(s2 * scale) : 0.f;
    float p3 = valid ? __expf(s3 * scale) : 0.f;
    lsum[0] += p0; lsum[1] += p1; lsum[2] += p2; lsum[3] += p3;
    if (q8 == 0) {
      float4 pw;
      pw.x = p0; pw.y = p1; pw.z = p2; pw.w = p3;
      *(float4*)&p_lds[w][t][0] = pw;
    }
    asm volatile("s_waitcnt lgkmcnt(0)" ::: "memory");  // p visible in-wave
    __builtin_amdgcn_sched_barrier(0);

    // ---- PV ----
    const float* vb = kb + 1024;
#pragma unroll
    for (int tt = 0; tt < TILE; ++tt) {
      float p = p_lds[w][tt][j];
      float4 Va = LD4(vb + tt * 128 + (((ds * 2) ^ tt) << 2));
      float4 Vb = LD4(vb + tt * 128 + (((ds * 2 + 1) ^ tt) << 2));
      out[0] += p * Va.x; out[1] += p * Va.y;
      out[2] += p * Va.z; out[3] += p * Va.w;
      out[4] += p * Vb.x; out[5] += p * Vb.y;
      out[6] += p * Vb.z; out[7] += p * Vb.w;
    }
  }

  // ---- in-wave lsum reduce over the 8 t-lanes (q8 copies identical) ----
#pragma unroll
  for (int m = 1; m <= 4; m <<= 1) {
    lsum[0] += __shfl_xor(lsum[0], m, 64);
    lsum[1] += __shfl_xor(lsum[1], m, 64);
    lsum[2] += __shfl_xor(lsum[2], m, 64);
    lsum[3] += __shfl_xor(lsum[3], m, 64);
  }

  // ---- cross-wave combine ----
  float4 oa, ob;
  oa.x = out[0]; oa.y = out[1]; oa.z = out[2]; oa.w = out[3];
  ob.x = out[4]; ob.y = out[5]; ob.z = out[6]; ob.w = out[7];
  *(float4*)&out_comb[w][j][ds * 8 + 0] = oa;
  *(float4*)&out_comb[w][j][ds * 8 + 4] = ob;
  if (l == 0) {
#pragma unroll
    for (int h = 0; h < NREP; ++h) l_comb[w][h] = lsum[h];
  }
  __syncthreads();
  for (int idx = tid; idx < NREP * HD; idx += 256) {
    int jj = idx >> 7, d = idx & (HD - 1);
    float s = out_comb[0][jj][d] + out_comb[1][jj][d] + out_comb[2][jj][d] +
              out_comb[3][jj][d];
    partial_o[((size_t)(gid * NREP + jj) * nsplit + split) * HD + d] = s;
  }
  if (tid < NREP) {
    partial_l[(gid * NREP + tid) * nsplit + split] =
        l_comb[0][tid] + l_comb[1][tid] + l_comb[2][tid] + l_comb[3][tid];
  }
}

// ---------------------------------------------------------------------------
// Kernel 3: combine splits + new-token contribution (m=0 everywhere).
// ---------------------------------------------------------------------------
__global__ __launch_bounds__(128) void combine_kernel(
    const float* __restrict__ q_rope, const float* __restrict__ k_new,
    const float* __restrict__ v_new, const float* __restrict__ partial_l,
    const float* __restrict__ partial_o, float* __restrict__ attn_out,
    int nsplit) {
  int h = blockIdx.x;
  int g = h >> 2;
  int tid = threadIdx.x;
  __shared__ float sl[512];
  __shared__ float sp[128];
  sp[tid] = q_rope[h * HD + tid] * k_new[g * HD + tid];
  for (int i = tid; i < nsplit; i += 128) sl[i] = partial_l[h * nsplit + i];
  __syncthreads();
  for (int s = 64; s > 0; s >>= 1) {
    if (tid < s) sp[tid] += sp[tid + s];
    __syncthreads();
  }
  float e_new = __expf(sp[0] * 0.08838834764831845f);
  float L = e_new;
  for (int s = 0; s < nsplit; ++s) L += sl[s];
  float acc = e_new * v_new[g * HD + tid];
#pragma unroll 4
  for (int s = 0; s < nsplit; ++s)
    acc += partial_o[((size_t)h * nsplit + s) * HD + tid];
  attn_out[h * HD + tid] = acc / L;
}

// ---------------------------------------------------------------------------
// Kernel 4: out = attn @ wo.T (unchanged).
// ---------------------------------------------------------------------------
__global__ __launch_bounds__(256) void out_gemv_kernel(
    const float* __restrict__ attn, const float* __restrict__ wo,
    float* __restrict__ out) {
  int row = blockIdx.x * 4 + (threadIdx.x >> 6);
  int lane = threadIdx.x & 63;
  const float4* a4 = (const float4*)attn;
  const float4* w4 = (const float4*)(wo + (size_t)row * DIM);
  float a = 0.f;
#pragma unroll 4
  for (int c = lane; c < DIM / 4; c += 64) {
    float4 av = a4[c];
    float4 wv = w4[c];
    a += av.x * wv.x + av.y * wv.y + av.z * wv.z + av.w * wv.w;
  }
  for (int off = 32; off > 0; off >>= 1) a += __shfl_down(a, off, 64);
  if (lane == 0) out[row] = a;
}

extern "C" void kernel_launch(void* const* d_in, const int* in_sizes, int n_in,
                              void* d_out, int out_size, void* d_ws,
                              size_t ws_size, hipStream_t stream) {
  const float* x       = (const float*)d_in[0];
  const float* fc      = (const float*)d_in[1];
  const float* fs      = (const float*)d_in[2];
  const float* k_cache = (const float*)d_in[3];
  const float* v_cache = (const float*)d_in[4];
  const float* wq      = (const float*)d_in[5];
  const float* wk      = (const float*)d_in[6];
  const float* wv      = (const float*)d_in[7];
  const float* wo      = (const float*)d_in[8];
  float* out = (float*)d_out;

  int start_pos = in_sizes[3] / (NKV * HD);  // cache length (32767)
  int nsplit = (start_pos + PBLK - 1) / PBLK;  // 32 -> grid 256 = 1 block/CU

  float* ws = (float*)d_ws;
  float* q_rope    = ws;                        // 4096
  float* k_new     = ws + 4096;                 // 1024
  float* v_new     = ws + 5120;                 // 1024
  float* attn_out  = ws + 6144;                 // 4096
  float* partial_l = ws + 10240;                // NH*nsplit
  float* partial_o = partial_l + NH * nsplit;   // NH*nsplit*HD

  qkv_rope_kernel<<<768, 256, 0, stream>>>(x, fc, fs, wq, wk, wv, q_rope,
                                           k_new, v_new);
  attn_partial_kernel<<<NKV * nsplit, 256, 0, stream>>>(
      q_rope, k_cache, v_cache, k_new, v_new, partial_l, partial_o,
      start_pos, nsplit);
  combine_kernel<<<NH, 128, 0, stream>>>(q_rope, k_new, v_new, partial_l,
                                         partial_o, attn_out, nsplit);
  out_gemv_kernel<<<1024, 256, 0, stream>>>(attn_out, wo, out);
}